// Round 3
// baseline (245.886 us; speedup 1.0000x reference)
//
#include <hip/hip_runtime.h>
#include <hip/hip_bf16.h>
#include <stdint.h>

// ---- types -----------------------------------------------------------------
typedef __bf16 bf16_t;
typedef __bf16 bf16x8 __attribute__((ext_vector_type(8)));
typedef __bf16 bf16x4 __attribute__((ext_vector_type(4)));
typedef float  f32x4  __attribute__((ext_vector_type(4)));

#define MFMA16(a, b, c) __builtin_amdgcn_mfma_f32_16x16x32_bf16((a), (b), (c), 0, 0, 0)

__device__ __forceinline__ void gload_lds16(const void* g, void* l) {
  __builtin_amdgcn_global_load_lds((const __attribute__((address_space(1))) void*)g,
                                   (__attribute__((address_space(3))) void*)l, 16, 0, 0);
}

// register-only lane exchanges (gfx950): both operands are read-write
__device__ __forceinline__ void permlane32_swap(uint32_t& a, uint32_t& b) {
  asm("v_permlane32_swap_b32 %0, %1" : "+v"(a), "+v"(b));
}
__device__ __forceinline__ void permlane16_swap(uint32_t& a, uint32_t& b) {
  asm("v_permlane16_swap_b32 %0, %1" : "+v"(a), "+v"(b));
}

// pack exp2(a), exp2(b) into one u32 of 2 bf16
__device__ __forceinline__ uint32_t pack_e2(float a, float b) {
  union { bf16_t h[2]; uint32_t u; } p;
  p.h[0] = (bf16_t)__builtin_amdgcn_exp2f(a);
  p.h[1] = (bf16_t)__builtin_amdgcn_exp2f(b);
  return p.u;
}

// ---- problem constants -----------------------------------------------------
// B=2, N=4096, NY=4096, ENC=768, DEC=512, H=8, D=64, SCALE=0.125
#define QSCALE 0.18033688011112042f
#define NE_X   4194304UL
#define NE_Y   6291456UL
#define NE_WQ  262144UL
#define NE_WKV 786432UL
#define NE_WP  262144UL
#define NE_BP  512UL

// ---- detect dtype + decode mask to multiplicative bf16 (1=keep, 0=masked) --
__global__ void detect_and_mask(const uint16_t* __restrict__ xu,
                                const uint8_t* __restrict__ mk,
                                int* __restrict__ flags, bf16_t* __restrict__ mmul) {
  __shared__ int cbf, c3f1, c3f3, cnz;
  const int t = threadIdx.x;
  if (t == 0) { cbf = 0; c3f1 = 0; c3f3 = 0; cnz = 0; }
  __syncthreads();
  if (blockIdx.x == 0) {
    int local = 0;
    for (int i = t; i < 2048; i += 256) {
      uint16_t u = xu[2 * i];
      int e = (u >> 7) & 0xFF;
      if (u == 0 || (e >= 0x66 && e <= 0x88)) local++;
    }
    atomicAdd(&cbf, local);
  }
  int l1 = 0, l3 = 0, lnz = 0;
  for (int i = t; i < 4096; i += 256) {
    uint8_t b = mk[i];
    int p = i & 3;
    if (p == 1 && b == 0x3F) l1++;
    if (p == 3 && b == 0x3F) l3++;
    if (p != 0 && b != 0) lnz++;
  }
  atomicAdd(&c3f1, l1);
  atomicAdd(&c3f3, l3);
  atomicAdd(&cnz, lnz);
  __syncthreads();
  if (blockIdx.x == 0 && t == 0) flags[0] = (cbf > 1536) ? 1 : 0;
  const int fmt = (c3f1 > 0) ? 2 : (c3f3 > 0) ? 3 : (cnz > 0) ? 0 : 1;  // 0=bool8 1=i32 2=bf16 3=f32
  const int i = blockIdx.x * 256 + t;  // 32 blocks x 256 = 8192
  bool on;
  if (fmt == 0)      on = mk[i] != 0;
  else if (fmt == 1) on = ((const int*)mk)[i] != 0;
  else if (fmt == 2) on = (((const uint16_t*)mk)[i] & 0x7FFF) != 0;
  else               on = ((const float*)mk)[i] != 0.0f;
  mmul[i] = on ? (bf16_t)0.0f : (bf16_t)1.0f;  // mask=true means EXCLUDE
}

// ---- convert all float inputs to packed bf16 workspace (Wq pre-scaled) -----
__global__ void convert_all(const void* __restrict__ x, const void* __restrict__ y,
                            const void* __restrict__ wq, const void* __restrict__ wkv,
                            const void* __restrict__ wp, const void* __restrict__ bp,
                            uint16_t* __restrict__ dst, const int* __restrict__ flags) {
  const size_t E0 = NE_X, E1 = E0 + NE_Y, E2 = E1 + NE_WQ, E3 = E2 + NE_WKV,
               E4 = E3 + NE_WP, E5 = E4 + NE_BP;
  size_t i8 = ((size_t)blockIdx.x * 256 + threadIdx.x) * 8;
  if (i8 >= E5) return;
  const void* src; size_t off;
  if      (i8 < E0) { src = x;   off = i8; }
  else if (i8 < E1) { src = y;   off = i8 - E0; }
  else if (i8 < E2) { src = wq;  off = i8 - E1; }
  else if (i8 < E3) { src = wkv; off = i8 - E2; }
  else if (i8 < E4) { src = wp;  off = i8 - E3; }
  else              { src = bp;  off = i8 - E4; }
  const bool isWq = (i8 >= E1 && i8 < E2);
  if (flags[0] && !isWq) {
    *(uint4*)(dst + i8) = *(const uint4*)((const uint16_t*)src + off);
    return;
  }
  float v[8];
  if (flags[0]) {  // bf16 source (Wq path): unpack
    const uint16_t* u = (const uint16_t*)src + off;
    for (int j = 0; j < 8; ++j) {
      union { uint32_t q; float f; } c; c.q = ((uint32_t)u[j]) << 16; v[j] = c.f;
    }
  } else {
    const float* f = (const float*)src + off;
    float4 a = *(const float4*)f;
    float4 b2 = *(const float4*)(f + 4);
    v[0] = a.x; v[1] = a.y; v[2] = a.z; v[3] = a.w;
    v[4] = b2.x; v[5] = b2.y; v[6] = b2.z; v[7] = b2.w;
  }
  const float sc = isWq ? QSCALE : 1.0f;
  union { bf16_t h[8]; uint4 u; } pk;
  for (int j = 0; j < 8; ++j) pk.h[j] = (bf16_t)(v[j] * sc);
  *(uint4*)(dst + i8) = pk.u;
}

// ---- GEMM: C[M x Nc] = A[M x K] @ W[Nc x K]^T, 128x128 tile, BK=32 ---------
template <int K, int MODE>
__launch_bounds__(256, 2)
__global__ void gemm_bt(const bf16_t* __restrict__ A, const bf16_t* __restrict__ W,
                        const bf16_t* __restrict__ bias, void* __restrict__ C,
                        bf16_t* __restrict__ Vt, const int* __restrict__ flags, int Ncols) {
  __shared__ __align__(16) char lds[16384];
  char* ldsA = lds;
  char* ldsW = lds + 8192;
  const int t = threadIdx.x;
  const int w = t >> 6, lane = t & 63, quad = lane >> 4, l16 = lane & 15;
  const int wr = w >> 1, wc = w & 1;
  const int m0 = blockIdx.y * 128, n0 = blockIdx.x * 128;

  f32x4 acc[4][4] = {};
  const int rowS = t >> 2, uS = t & 3;

  for (int k0 = 0; k0 < K; k0 += 32) {
    __syncthreads();
    for (int i = 0; i < 2; ++i) {
      int row = i * 64 + rowS;
      int c = uS ^ ((row >> 1) & 3);
      gload_lds16(A + (size_t)(m0 + row) * K + k0 + c * 8, ldsA + i * 4096 + w * 1024);
      gload_lds16(W + (size_t)(n0 + row) * K + k0 + c * 8, ldsW + i * 4096 + w * 1024);
    }
    __syncthreads();
    bf16x8 af[4], bfr[4];
    for (int mt = 0; mt < 4; ++mt) {
      int row = wr * 64 + mt * 16 + l16;
      int us = quad ^ ((row >> 1) & 3);
      af[mt] = *(const bf16x8*)(ldsA + row * 64 + us * 16);
    }
    for (int nt = 0; nt < 4; ++nt) {
      int row = wc * 64 + nt * 16 + l16;
      int us = quad ^ ((row >> 1) & 3);
      bfr[nt] = *(const bf16x8*)(ldsW + row * 64 + us * 16);
    }
    for (int mt = 0; mt < 4; ++mt)
      for (int nt = 0; nt < 4; ++nt)
        acc[mt][nt] = MFMA16(af[mt], bfr[nt], acc[mt][nt]);
  }

  const int mbase = m0 + wr * 64;
  for (int nt = 0; nt < 4; ++nt) {
    const int col = n0 + wc * 64 + nt * 16 + l16;
    if (MODE == 1 && col >= 512) {
      const int hd = col - 512;                  // h*64 + d
      const int hh = hd >> 6, d = hd & 63;
      const int dt = d >> 4, l15 = d & 15;
      for (int mt = 0; mt < 4; ++mt) {
        int m = mbase + mt * 16 + quad * 4;      // +r over r
        int bb = m >> 12, keyg = m & 4095;
        int kt = keyg >> 6, keyin = keyg & 63;
        int kc = (keyin >> 5) & 1, jq = (keyin >> 3) & 3, j0 = keyin & 7;  // j0 in {0,4}
        const bf16_t* mmp = bias + bb * 4096 + keyg;
        union { bf16_t h4[4]; uint2 u; } pk;
        for (int r = 0; r < 4; ++r) pk.h4[r] = (bf16_t)(acc[mt][nt][r] * (float)mmp[r]);
        size_t base = (((size_t)(bb * 8 + hh) * 64 + kt) * 8 + dt * 2 + kc) * 1024
                      + (jq * 16 + l15) * 16 + j0 * 2;
        *(uint2*)((char*)Vt + base) = pk.u;
      }
    } else if (MODE == 1) {
      for (int mt = 0; mt < 4; ++mt) {
        int m = mbase + mt * 16 + quad * 4;
        for (int r = 0; r < 4; ++r)
          ((bf16_t*)C)[(size_t)(m + r) * 512 + col] = (bf16_t)acc[mt][nt][r];
      }
    } else if (MODE == 0) {
      for (int mt = 0; mt < 4; ++mt) {
        int m = mbase + mt * 16 + quad * 4;
        for (int r = 0; r < 4; ++r)
          ((bf16_t*)C)[(size_t)(m + r) * Ncols + col] = (bf16_t)acc[mt][nt][r];
      }
    } else {  // MODE 2
      const float bv = (float)bias[col];
      const bool obf = (flags[0] != 0);
      for (int mt = 0; mt < 4; ++mt) {
        int m = mbase + mt * 16 + quad * 4;
        for (int r = 0; r < 4; ++r) {
          float v = acc[mt][nt][r] + bv;
          if (obf) ((bf16_t*)C)[(size_t)(m + r) * Ncols + col] = (bf16_t)v;
          else     ((float*)C)[(size_t)(m + r) * Ncols + col] = v;
        }
      }
    }
  }
}

// ---- fused flash attention, 128 q / block, 32 q / wave ---------------------
// No online max: scores are bounded (pre-scaled Wq), softmax shift-invariant.
// T15 1-tile software pipeline: iteration kt issues QK MFMA for tile kt FIRST,
// then softmax+PV for tile kt-1 (scores in zA/zB register ping-pong, statically
// indexed by unrolled kk). Matrix pipe (QK) overlaps VALU (softmax) per-wave.
// P transpose stays fully in-register (cvt_pk + permlane swaps). 8-slot K ring
// (64KB), ONE barrier per 4 tiles. h=bid&7 pins each head to one XCD.
__launch_bounds__(256, 2)
__global__ void attn(const bf16_t* __restrict__ Qb, const bf16_t* __restrict__ Kb,
                     const bf16_t* __restrict__ Vfb, const bf16_t* __restrict__ mmul,
                     bf16_t* __restrict__ Ob) {
  const int t = threadIdx.x, w = t >> 6, lane = t & 63, quad = lane >> 4, l16 = lane & 15;
  const int bid = blockIdx.x;
  const int h = bid & 7;            // XCD-pinned: bid%8 -> same XCD
  const int b = (bid >> 3) & 1;
  const int q0 = (bid >> 4) * 128;

  __shared__ __align__(16) char lds[65536];  // K ring: 8 x 8KB; Q staged in slots 4,5
  char* Qs = lds + 32768;

  // stage Q (128 q x 64 d) + K tiles 0..3
  for (int i = 0; i < 4; ++i) {
    int row = i * 32 + (t >> 3);
    int c = (t & 7) ^ (row & 7);
    gload_lds16(Qb + (size_t)(b * 4096 + q0 + row) * 512 + h * 64 + c * 8,
                Qs + i * 4096 + w * 1024);
  }
  for (int kt = 0; kt < 4; ++kt)
    for (int i = 0; i < 2; ++i) {
      int row = i * 32 + (t >> 3);
      int c = (t & 7) ^ (row & 7);
      gload_lds16(Kb + (size_t)(b * 4096 + kt * 64 + row) * 512 + h * 64 + c * 8,
                  lds + kt * 8192 + i * 4096 + w * 1024);
    }
  __syncthreads();

  bf16x8 qf[2][2];
  for (int ng = 0; ng < 2; ++ng)
    for (int kc = 0; kc < 2; ++kc) {
      int row = 32 * w + 16 * ng + l16;
      int u = (4 * kc + quad) ^ (row & 7);
      qf[ng][kc] = *(const bf16x8*)(Qs + row * 128 + u * 16);
    }
  __syncthreads();  // Q reads done before ring slots 4,5 are overwritten

  f32x4 o[2][4] = {};
  f32x4 lacc[2] = {};
  f32x4 zA[2][4], zB[2][4];  // score ping-pong: even kt -> zA, odd kt -> zB
  const char* Vfbase = (const char*)Vfb + (size_t)(b * 8 + h) * 524288;  // 64*8*1024

  auto load_kf = [&](bf16x8 (&kf)[4][2], int kt) {
    const char* Kl = lds + (kt & 7) * 8192;
    for (int mt = 0; mt < 4; ++mt)
      for (int kc = 0; kc < 2; ++kc) {
        int row = mt * 16 + l16;
        int u = (4 * kc + quad) ^ (row & 7);
        kf[mt][kc] = *(const bf16x8*)(Kl + row * 128 + u * 16);
      }
  };
  auto qk = [&](f32x4 (&zN)[2][4], bf16x8 (&kf)[4][2]) {
    __builtin_amdgcn_s_setprio(1);
    for (int ng = 0; ng < 2; ++ng)
      for (int mt = 0; mt < 4; ++mt) {
        f32x4 zz = {};
        zz = MFMA16(kf[mt][0], qf[ng][0], zz);
        zN[ng][mt] = MFMA16(kf[mt][1], qf[ng][1], zz);
      }
    __builtin_amdgcn_s_setprio(0);
  };
  auto loadv = [&](bf16x8 (&vf)[4][2], bf16x8 (&mf)[2], int ktp) {
    const int kt0 = ktp * 64;
    mf[0] = *(const bf16x8*)(mmul + b * 4096 + kt0 + quad * 8);
    mf[1] = *(const bf16x8*)(mmul + b * 4096 + kt0 + 32 + quad * 8);
    const char* Vtile = Vfbase + (size_t)ktp * 8192;
    for (int dt = 0; dt < 4; ++dt)
      for (int kc = 0; kc < 2; ++kc)
        vf[dt][kc] = *(const bf16x8*)(Vtile + (dt * 2 + kc) * 1024 + lane * 16);
  };
  auto softpv = [&](f32x4 (&zO)[2][4], bf16x8 (&vf)[4][2], bf16x8 (&mf)[2]) {
    bf16x8 pf[2][2];
    for (int ng = 0; ng < 2; ++ng) {
      uint32_t w0[4], w1[4];
      for (int mt = 0; mt < 4; ++mt) {
        w0[mt] = pack_e2(zO[ng][mt][0], zO[ng][mt][1]);
        w1[mt] = pack_e2(zO[ng][mt][2], zO[ng][mt][3]);
      }
      for (int kc = 0; kc < 2; ++kc) {
        uint32_t a0 = w0[2 * kc], b0 = w0[2 * kc + 1];
        uint32_t a1 = w1[2 * kc], b1 = w1[2 * kc + 1];
        permlane32_swap(a0, b0); permlane16_swap(a0, b0);
        permlane32_swap(a1, b1); permlane16_swap(a1, b1);
        union { uint32_t u[4]; bf16x8 v; } P;
        P.u[0] = a0; P.u[1] = a1; P.u[2] = b0; P.u[3] = b1;
        pf[ng][kc] = P.v;
      }
    }
    __builtin_amdgcn_s_setprio(1);
    for (int ng = 0; ng < 2; ++ng) {
      lacc[ng] = MFMA16(pf[ng][0], mf[0], lacc[ng]);
      lacc[ng] = MFMA16(pf[ng][1], mf[1], lacc[ng]);
    }
    for (int dt = 0; dt < 4; ++dt)
      for (int kc = 0; kc < 2; ++kc) {
        o[0][dt] = MFMA16(pf[0][kc], vf[dt][kc], o[0][dt]);
        o[1][dt] = MFMA16(pf[1][kc], vf[dt][kc], o[1][dt]);
      }
    __builtin_amdgcn_s_setprio(0);
  };

  for (int ktg = 0; ktg < 16; ++ktg) {
    const int ktA = ktg * 4;
    __syncthreads();  // ring slots ktA..ktA+3 landed; their consumers below
    // prefetch tiles ktA+4..ktA+7 into their ring slots (disjoint from current 4)
    if (ktg + 1 < 16) {
      for (int kk = 4; kk < 8; ++kk) {
        const int kt = ktA + kk;
        for (int i = 0; i < 2; ++i) {
          int row = i * 32 + (t >> 3);
          int c = (t & 7) ^ (row & 7);
          gload_lds16(Kb + (size_t)(b * 4096 + kt * 64 + row) * 512 + h * 64 + c * 8,
                      lds + (kt & 7) * 8192 + i * 4096 + w * 1024);
        }
      }
    }
#pragma unroll
    for (int kk = 0; kk < 4; ++kk) {
      const int kt = ktA + kk;
      const bool doC = (ktg + kk) > 0;   // uniform; constant-true for kk>0
      bf16x8 vf[4][2], mf[2], kf[4][2];
      if (doC) loadv(vf, mf, kt - 1);    // V/mask for PREVIOUS tile, issued early
      load_kf(kf, kt);                   // K frags for THIS tile (LDS)
      if (kk & 1) {
        qk(zB, kf);                      // matrix pipe: tile kt
        if (doC) softpv(zA, vf, mf);     // VALU+PV: tile kt-1 (overlaps QK)
      } else {
        qk(zA, kf);
        if (doC) softpv(zB, vf, mf);
      }
    }
  }
  // drain: tile 63 (written to zB at kk=3)
  {
    bf16x8 vf[4][2], mf[2];
    loadv(vf, mf, 63);
    softpv(zB, vf, mf);
  }

  // epilogue: O / l, store bf16 (C-layout, no shuffles)
  for (int ng = 0; ng < 2; ++ng) {
    float inv[4];
    for (int r = 0; r < 4; ++r) inv[r] = 1.0f / lacc[ng][r];
    for (int dt = 0; dt < 4; ++dt)
      for (int r = 0; r < 4; ++r) {
        int q = q0 + 32 * w + 16 * ng + quad * 4 + r;
        int col = h * 64 + dt * 16 + l16;
        Ob[(size_t)(b * 4096 + q) * 512 + col] = (bf16_t)(o[ng][dt][r] * inv[r]);
      }
  }
}

// ---- launch ----------------------------------------------------------------
extern "C" void kernel_launch(void* const* d_in, const int* in_sizes, int n_in,
                              void* d_out, int out_size, void* d_ws, size_t ws_size,
                              hipStream_t stream) {
  const void* x   = d_in[0];
  const void* y   = d_in[1];
  const void* msk = d_in[2];
  const void* Wq  = d_in[3];
  const void* Wkv = d_in[4];
  const void* Wp  = d_in[5];
  const void* bp  = d_in[6];

  char* ws = (char*)d_ws;
  bf16_t* Xb   = (bf16_t*)(ws + 0);           //  8 MB  [8192 x 512]
  bf16_t* Yb   = (bf16_t*)(ws + 8388608);     // 12 MB  [8192 x 768]
  bf16_t* Wqb  = (bf16_t*)(ws + 20971520);    // 0.5 MB (pre-scaled by QSCALE)
  bf16_t* Wkvb = (bf16_t*)(ws + 21495808);    // 1.5 MB
  bf16_t* Wpb  = (bf16_t*)(ws + 23068672);    // 0.5 MB
  bf16_t* bpb  = (bf16_t*)(ws + 23592960);    // 1 KB
  bf16_t* mmul = (bf16_t*)(ws + 23593984);    // 16 KB  [2][4096] 0/1
  int*    flags = (int*)(ws + 23610368);      // 64 B
  bf16_t* Kbuf  = (bf16_t*)(ws + 25165824);   //  8 MB  [8192 x 512]
  bf16_t* Vfrag = (bf16_t*)(ws + 33554432);   //  8 MB  fragment-order V, mask-zeroed
  bf16_t* Qbuf  = (bf16_t*)(ws + 8388608);    //  8 MB  (aliases Yb, dead by then)
  bf16_t* Obuf  = (bf16_t*)(ws + 0);          //  8 MB  (aliases Xb, dead by then)

  hipLaunchKernelGGL(detect_and_mask, dim3(32), dim3(256), 0, stream,
                     (const uint16_t*)x, (const uint8_t*)msk, flags, mmul);
  hipLaunchKernelGGL(convert_all, dim3(5761), dim3(256), 0, stream,
                     x, y, Wq, Wkv, Wp, bp, (uint16_t*)ws, flags);
  // KV projection; V side written in MFMA fragment order + mask-zeroed
  hipLaunchKernelGGL((gemm_bt<768, 1>), dim3(8, 64), dim3(256), 0, stream,
                     Yb, Wkvb, mmul, (void*)Kbuf, Vfrag, flags, 1024);
  // Q projection (scores pre-scaled via Wqb)
  hipLaunchKernelGGL((gemm_bt<512, 0>), dim3(4, 64), dim3(256), 0, stream,
                     Xb, Wqb, (const bf16_t*)nullptr, (void*)Qbuf, (bf16_t*)nullptr, flags, 512);
  // fused attention (1-D grid, XCD-pinned heads)
  hipLaunchKernelGGL(attn, dim3(512), dim3(256), 0, stream,
                     Qbuf, Kbuf, Vfrag, mmul, Obuf);
  // output projection + bias, dtype per flag
  hipLaunchKernelGGL((gemm_bt<512, 2>), dim3(4, 64), dim3(256), 0, stream,
                     Obuf, Wpb, bpb, d_out, (bf16_t*)nullptr, flags, 512);
}

// Round 5
// 241.616 us; speedup vs baseline: 1.0177x; 1.0177x over previous
//
#include <hip/hip_runtime.h>
#include <hip/hip_bf16.h>
#include <stdint.h>

// ---- types -----------------------------------------------------------------
typedef __bf16 bf16_t;
typedef __bf16 bf16x8 __attribute__((ext_vector_type(8)));
typedef __bf16 bf16x4 __attribute__((ext_vector_type(4)));
typedef float  f32x4  __attribute__((ext_vector_type(4)));

#define MFMA16(a, b, c) __builtin_amdgcn_mfma_f32_16x16x32_bf16((a), (b), (c), 0, 0, 0)

__device__ __forceinline__ void gload_lds16(const void* g, void* l) {
  __builtin_amdgcn_global_load_lds((const __attribute__((address_space(1))) void*)g,
                                   (__attribute__((address_space(3))) void*)l, 16, 0, 0);
}

// ---- problem constants -----------------------------------------------------
// B=2, N=4096, NY=4096, ENC=768, DEC=512, H=8, D=64, SCALE=0.125
#define QSCALE 0.18033688011112042f
#define NE_X   4194304UL
#define NE_Y   6291456UL
#define NE_WQ  262144UL
#define NE_WKV 786432UL
#define NE_WP  262144UL
#define NE_BP  512UL

// ---- detect dtype + decode mask to multiplicative bf16 (1=keep, 0=masked) --
__global__ void detect_and_mask(const uint16_t* __restrict__ xu,
                                const uint8_t* __restrict__ mk,
                                int* __restrict__ flags, bf16_t* __restrict__ mmul) {
  __shared__ int cbf, c3f1, c3f3, cnz;
  const int t = threadIdx.x;
  if (t == 0) { cbf = 0; c3f1 = 0; c3f3 = 0; cnz = 0; }
  __syncthreads();
  if (blockIdx.x == 0) {
    int local = 0;
    for (int i = t; i < 2048; i += 256) {
      uint16_t u = xu[2 * i];
      int e = (u >> 7) & 0xFF;
      if (u == 0 || (e >= 0x66 && e <= 0x88)) local++;
    }
    atomicAdd(&cbf, local);
  }
  int l1 = 0, l3 = 0, lnz = 0;
  for (int i = t; i < 4096; i += 256) {
    uint8_t b = mk[i];
    int p = i & 3;
    if (p == 1 && b == 0x3F) l1++;
    if (p == 3 && b == 0x3F) l3++;
    if (p != 0 && b != 0) lnz++;
  }
  atomicAdd(&c3f1, l1);
  atomicAdd(&c3f3, l3);
  atomicAdd(&cnz, lnz);
  __syncthreads();
  if (blockIdx.x == 0 && t == 0) flags[0] = (cbf > 1536) ? 1 : 0;
  const int fmt = (c3f1 > 0) ? 2 : (c3f3 > 0) ? 3 : (cnz > 0) ? 0 : 1;  // 0=bool8 1=i32 2=bf16 3=f32
  const int i = blockIdx.x * 256 + t;  // 32 blocks x 256 = 8192
  bool on;
  if (fmt == 0)      on = mk[i] != 0;
  else if (fmt == 1) on = ((const int*)mk)[i] != 0;
  else if (fmt == 2) on = (((const uint16_t*)mk)[i] & 0x7FFF) != 0;
  else               on = ((const float*)mk)[i] != 0.0f;
  mmul[i] = on ? (bf16_t)0.0f : (bf16_t)1.0f;  // mask=true means EXCLUDE
}

// ---- convert all float inputs to packed bf16 workspace (Wq pre-scaled) -----
__global__ void convert_all(const void* __restrict__ x, const void* __restrict__ y,
                            const void* __restrict__ wq, const void* __restrict__ wkv,
                            const void* __restrict__ wp, const void* __restrict__ bp,
                            uint16_t* __restrict__ dst, const int* __restrict__ flags) {
  const size_t E0 = NE_X, E1 = E0 + NE_Y, E2 = E1 + NE_WQ, E3 = E2 + NE_WKV,
               E4 = E3 + NE_WP, E5 = E4 + NE_BP;
  size_t i8 = ((size_t)blockIdx.x * 256 + threadIdx.x) * 8;
  if (i8 >= E5) return;
  const void* src; size_t off;
  if      (i8 < E0) { src = x;   off = i8; }
  else if (i8 < E1) { src = y;   off = i8 - E0; }
  else if (i8 < E2) { src = wq;  off = i8 - E1; }
  else if (i8 < E3) { src = wkv; off = i8 - E2; }
  else if (i8 < E4) { src = wp;  off = i8 - E3; }
  else              { src = bp;  off = i8 - E4; }
  const bool isWq = (i8 >= E1 && i8 < E2);
  if (flags[0] && !isWq) {
    *(uint4*)(dst + i8) = *(const uint4*)((const uint16_t*)src + off);
    return;
  }
  float v[8];
  if (flags[0]) {  // bf16 source (Wq path): unpack
    const uint16_t* u = (const uint16_t*)src + off;
    for (int j = 0; j < 8; ++j) {
      union { uint32_t q; float f; } c; c.q = ((uint32_t)u[j]) << 16; v[j] = c.f;
    }
  } else {
    const float* f = (const float*)src + off;
    float4 a = *(const float4*)f;
    float4 b2 = *(const float4*)(f + 4);
    v[0] = a.x; v[1] = a.y; v[2] = a.z; v[3] = a.w;
    v[4] = b2.x; v[5] = b2.y; v[6] = b2.z; v[7] = b2.w;
  }
  const float sc = isWq ? QSCALE : 1.0f;
  union { bf16_t h[8]; uint4 u; } pk;
  for (int j = 0; j < 8; ++j) pk.h[j] = (bf16_t)(v[j] * sc);
  *(uint4*)(dst + i8) = pk.u;
}

// ---- GEMM: C[M x Nc] = A[M x K] @ W[Nc x K]^T, 128x128 tile, BK=32 ---------
template <int K, int MODE>
__launch_bounds__(256, 2)
__global__ void gemm_bt(const bf16_t* __restrict__ A, const bf16_t* __restrict__ W,
                        const bf16_t* __restrict__ bias, void* __restrict__ C,
                        bf16_t* __restrict__ Vt, const int* __restrict__ flags, int Ncols) {
  __shared__ __align__(16) char lds[16384];
  char* ldsA = lds;
  char* ldsW = lds + 8192;
  const int t = threadIdx.x;
  const int w = t >> 6, lane = t & 63, quad = lane >> 4, l16 = lane & 15;
  const int wr = w >> 1, wc = w & 1;
  const int m0 = blockIdx.y * 128, n0 = blockIdx.x * 128;

  f32x4 acc[4][4] = {};
  const int rowS = t >> 2, uS = t & 3;

  for (int k0 = 0; k0 < K; k0 += 32) {
    __syncthreads();
    for (int i = 0; i < 2; ++i) {
      int row = i * 64 + rowS;
      int c = uS ^ ((row >> 1) & 3);
      gload_lds16(A + (size_t)(m0 + row) * K + k0 + c * 8, ldsA + i * 4096 + w * 1024);
      gload_lds16(W + (size_t)(n0 + row) * K + k0 + c * 8, ldsW + i * 4096 + w * 1024);
    }
    __syncthreads();
    bf16x8 af[4], bfr[4];
    for (int mt = 0; mt < 4; ++mt) {
      int row = wr * 64 + mt * 16 + l16;
      int us = quad ^ ((row >> 1) & 3);
      af[mt] = *(const bf16x8*)(ldsA + row * 64 + us * 16);
    }
    for (int nt = 0; nt < 4; ++nt) {
      int row = wc * 64 + nt * 16 + l16;
      int us = quad ^ ((row >> 1) & 3);
      bfr[nt] = *(const bf16x8*)(ldsW + row * 64 + us * 16);
    }
    for (int mt = 0; mt < 4; ++mt)
      for (int nt = 0; nt < 4; ++nt)
        acc[mt][nt] = MFMA16(af[mt], bfr[nt], acc[mt][nt]);
  }

  const int mbase = m0 + wr * 64;
  for (int nt = 0; nt < 4; ++nt) {
    const int col = n0 + wc * 64 + nt * 16 + l16;
    if (MODE == 1 && col >= 512) {
      const int hd = col - 512;                  // h*64 + d
      const int hh = hd >> 6, d = hd & 63;
      const int dt = d >> 4, l15 = d & 15;
      for (int mt = 0; mt < 4; ++mt) {
        int m = mbase + mt * 16 + quad * 4;      // +r over r
        int bb = m >> 12, keyg = m & 4095;
        int kt = keyg >> 6, keyin = keyg & 63;
        int kc = (keyin >> 5) & 1, jq = (keyin >> 3) & 3, j0 = keyin & 7;  // j0 in {0,4}
        const bf16_t* mmp = bias + bb * 4096 + keyg;
        union { bf16_t h4[4]; uint2 u; } pk;
        for (int r = 0; r < 4; ++r) pk.h4[r] = (bf16_t)(acc[mt][nt][r] * (float)mmp[r]);
        size_t base = (((size_t)(bb * 8 + hh) * 64 + kt) * 8 + dt * 2 + kc) * 1024
                      + (jq * 16 + l15) * 16 + j0 * 2;
        *(uint2*)((char*)Vt + base) = pk.u;
      }
    } else if (MODE == 1) {
      for (int mt = 0; mt < 4; ++mt) {
        int m = mbase + mt * 16 + quad * 4;
        for (int r = 0; r < 4; ++r)
          ((bf16_t*)C)[(size_t)(m + r) * 512 + col] = (bf16_t)acc[mt][nt][r];
      }
    } else if (MODE == 0) {
      for (int mt = 0; mt < 4; ++mt) {
        int m = mbase + mt * 16 + quad * 4;
        for (int r = 0; r < 4; ++r)
          ((bf16_t*)C)[(size_t)(m + r) * Ncols + col] = (bf16_t)acc[mt][nt][r];
      }
    } else {  // MODE 2
      const float bv = (float)bias[col];
      const bool obf = (flags[0] != 0);
      for (int mt = 0; mt < 4; ++mt) {
        int m = mbase + mt * 16 + quad * 4;
        for (int r = 0; r < 4; ++r) {
          float v = acc[mt][nt][r] + bv;
          if (obf) ((bf16_t*)C)[(size_t)(m + r) * Ncols + col] = (bf16_t)v;
          else     ((float*)C)[(size_t)(m + r) * Ncols + col] = v;
        }
      }
    }
  }
}

// ---- fused flash attention, 128 q / block, 16 q / wave, 8 waves ------------
// No online max: scores are bounded (pre-scaled Wq), softmax shift-invariant.
// 512-thread blocks -> 4 waves/SIMD (2 blocks/CU, 80KB LDS each) for latency
// hiding. K AND V staged via ring: 4 slots x (K 8KB + V 8KB); V-fragment tiles
// are lane-linear so global_load_lds applies. P via per-wave LDS round-trip
// (measured cheaper than permlane path). One barrier per 2 tiles.
// h=bid&7 pins each head to one XCD so K/V stay L2-resident.
__launch_bounds__(512, 4)
__global__ void attn(const bf16_t* __restrict__ Qb, const bf16_t* __restrict__ Kb,
                     const bf16_t* __restrict__ Vfb, const bf16_t* __restrict__ mmul,
                     bf16_t* __restrict__ Ob) {
  const int t = threadIdx.x, w = t >> 6, lane = t & 63, quad = lane >> 4, l16 = lane & 15;
  const int bid = blockIdx.x;
  const int h = bid & 7;            // XCD-pinned: bid%8 -> same XCD
  const int b = (bid >> 3) & 1;
  const int q0 = (bid >> 4) * 128;

  __shared__ __align__(16) char lds[81920];
  // ring: 4 slots x 16KB (K at +0, V at +8192) = [0,65536)
  // P: [65536,81920) 8 waves x 2KB; Q staging overlays P region.
  char* Pw = lds + 65536 + w * 2048;
  char* Qs = lds + 65536;

  const bf16_t* Kbase = Kb + (size_t)(b * 4096) * 512 + h * 64;
  const char* Vfbase = (const char*)Vfb + (size_t)(b * 8 + h) * 524288;  // 64*8*1024

  const int srow = w * 8 + (lane >> 3);          // staging row within 64
  const int sc8 = (lane & 7);                    // staging unit

  auto stage_tile = [&](int kt) {
    char* slot = lds + (kt & 3) * 16384;
    int c = sc8 ^ (srow & 7);
    gload_lds16(Kbase + (size_t)(kt * 64 + srow) * 512 + c * 8, slot + w * 1024);
    gload_lds16(Vfbase + (size_t)kt * 8192 + w * 1024 + lane * 16,
                slot + 8192 + w * 1024);
  };

  // stage Q (128 q x 64 d, 2 passes) into P region + K/V tiles 0,1
  for (int i = 0; i < 2; ++i) {
    int row = i * 64 + srow;
    int c = sc8 ^ (row & 7);
    gload_lds16(Qb + (size_t)(b * 4096 + q0 + row) * 512 + h * 64 + c * 8,
                Qs + i * 8192 + w * 1024);
  }
  stage_tile(0);
  stage_tile(1);
  __syncthreads();

  const int u0 = quad ^ (l16 & 7), u1 = (4 + quad) ^ (l16 & 7);
  bf16x8 qf[2];
  {
    int row = w * 16 + l16;
    qf[0] = *(const bf16x8*)(Qs + row * 128 + u0 * 16);
    qf[1] = *(const bf16x8*)(Qs + row * 128 + u1 * 16);
  }
  __syncthreads();  // Q reads done before P region reuse

  f32x4 o[4] = {};
  f32x4 lacc = {};

  auto process = [&](int kt) {
    const char* slot = lds + (kt & 3) * 16384;
    const int kt0 = kt * 64;
    // mask fragments (global, L1-hot)
    bf16x8 mf0 = *(const bf16x8*)(mmul + b * 4096 + kt0 + quad * 8);
    bf16x8 mf1 = *(const bf16x8*)(mmul + b * 4096 + kt0 + 32 + quad * 8);
    // K fragments
    bf16x8 kf[4][2];
    for (int mt = 0; mt < 4; ++mt) {
      kf[mt][0] = *(const bf16x8*)(slot + (mt * 16 + l16) * 128 + u0 * 16);
      kf[mt][1] = *(const bf16x8*)(slot + (mt * 16 + l16) * 128 + u1 * 16);
    }
    // S^T = K·Q^T (64k x 16q)
    f32x4 z[4];
    __builtin_amdgcn_s_setprio(1);
    for (int mt = 0; mt < 4; ++mt) {
      f32x4 zz = {};
      zz = MFMA16(kf[mt][0], qf[0], zz);
      z[mt] = MFMA16(kf[mt][1], qf[1], zz);
    }
    __builtin_amdgcn_s_setprio(0);
    // P = exp2(S), bf16, to per-wave LDS (swizzled)
    for (int mt = 0; mt < 4; ++mt) {
      bf16x4 pk;
      pk.x = (bf16_t)__builtin_amdgcn_exp2f(z[mt][0]);
      pk.y = (bf16_t)__builtin_amdgcn_exp2f(z[mt][1]);
      pk.z = (bf16_t)__builtin_amdgcn_exp2f(z[mt][2]);
      pk.w = (bf16_t)__builtin_amdgcn_exp2f(z[mt][3]);
      int c2 = (2 * mt + (quad >> 1)) ^ (l16 & 7);
      *(bf16x4*)(Pw + l16 * 128 + c2 * 16 + (quad & 1) * 8) = pk;
    }
    // V fragments (LDS, lane-linear, conflict-free)
    const char* Vs = slot + 8192;
    bf16x8 vf[4][2];
    for (int dt = 0; dt < 4; ++dt) {
      vf[dt][0] = *(const bf16x8*)(Vs + (dt * 2 + 0) * 1024 + lane * 16);
      vf[dt][1] = *(const bf16x8*)(Vs + (dt * 2 + 1) * 1024 + lane * 16);
    }
    // P fragments back (A-operand layout)
    bf16x8 pf[2];
    pf[0] = *(const bf16x8*)(Pw + l16 * 128 + u0 * 16);
    pf[1] = *(const bf16x8*)(Pw + l16 * 128 + u1 * 16);
    // l via mask MFMA; PV
    __builtin_amdgcn_s_setprio(1);
    lacc = MFMA16(pf[0], mf0, lacc);
    lacc = MFMA16(pf[1], mf1, lacc);
    for (int dt = 0; dt < 4; ++dt) {
      o[dt] = MFMA16(pf[0], vf[dt][0], o[dt]);
      o[dt] = MFMA16(pf[1], vf[dt][1], o[dt]);
    }
    __builtin_amdgcn_s_setprio(0);
  };

  for (int pg = 0; pg < 32; ++pg) {
    const int ktA = pg * 2;
    if (pg + 1 < 32) {          // prefetch next pair into the other 2 slots
      stage_tile(ktA + 2);
      stage_tile(ktA + 3);
    }
    process(ktA);
    process(ktA + 1);
    __syncthreads();            // one drain per 2 tiles: prefetch landed, slots free
  }

  // epilogue: O / l, store bf16 (C-layout, no shuffles)
  {
    float inv[4];
    for (int r = 0; r < 4; ++r) inv[r] = 1.0f / lacc[r];
    for (int dt = 0; dt < 4; ++dt)
      for (int r = 0; r < 4; ++r) {
        int q = q0 + w * 16 + quad * 4 + r;
        int col = h * 64 + dt * 16 + l16;
        Ob[(size_t)(b * 4096 + q) * 512 + col] = (bf16_t)(o[dt][r] * inv[r]);
      }
  }
}

// ---- launch ----------------------------------------------------------------
extern "C" void kernel_launch(void* const* d_in, const int* in_sizes, int n_in,
                              void* d_out, int out_size, void* d_ws, size_t ws_size,
                              hipStream_t stream) {
  const void* x   = d_in[0];
  const void* y   = d_in[1];
  const void* msk = d_in[2];
  const void* Wq  = d_in[3];
  const void* Wkv = d_in[4];
  const void* Wp  = d_in[5];
  const void* bp  = d_in[6];

  char* ws = (char*)d_ws;
  bf16_t* Xb   = (bf16_t*)(ws + 0);           //  8 MB  [8192 x 512]
  bf16_t* Yb   = (bf16_t*)(ws + 8388608);     // 12 MB  [8192 x 768]
  bf16_t* Wqb  = (bf16_t*)(ws + 20971520);    // 0.5 MB (pre-scaled by QSCALE)
  bf16_t* Wkvb = (bf16_t*)(ws + 21495808);    // 1.5 MB
  bf16_t* Wpb  = (bf16_t*)(ws + 23068672);    // 0.5 MB
  bf16_t* bpb  = (bf16_t*)(ws + 23592960);    // 1 KB
  bf16_t* mmul = (bf16_t*)(ws + 23593984);    // 16 KB  [2][4096] 0/1
  int*    flags = (int*)(ws + 23610368);      // 64 B
  bf16_t* Kbuf  = (bf16_t*)(ws + 25165824);   //  8 MB  [8192 x 512]
  bf16_t* Vfrag = (bf16_t*)(ws + 33554432);   //  8 MB  fragment-order V, mask-zeroed
  bf16_t* Qbuf  = (bf16_t*)(ws + 8388608);    //  8 MB  (aliases Yb, dead by then)
  bf16_t* Obuf  = (bf16_t*)(ws + 0);          //  8 MB  (aliases Xb, dead by then)

  hipLaunchKernelGGL(detect_and_mask, dim3(32), dim3(256), 0, stream,
                     (const uint16_t*)x, (const uint8_t*)msk, flags, mmul);
  hipLaunchKernelGGL(convert_all, dim3(5761), dim3(256), 0, stream,
                     x, y, Wq, Wkv, Wp, bp, (uint16_t*)ws, flags);
  // KV projection; V side written in MFMA fragment order + mask-zeroed
  hipLaunchKernelGGL((gemm_bt<768, 1>), dim3(8, 64), dim3(256), 0, stream,
                     Yb, Wkvb, mmul, (void*)Kbuf, Vfrag, flags, 1024);
  // Q projection (scores pre-scaled via Wqb)
  hipLaunchKernelGGL((gemm_bt<512, 0>), dim3(4, 64), dim3(256), 0, stream,
                     Xb, Wqb, (const bf16_t*)nullptr, (void*)Qbuf, (bf16_t*)nullptr, flags, 512);
  // fused attention (512 threads = 8 waves x 16q, 1-D grid, XCD-pinned heads)
  hipLaunchKernelGGL(attn, dim3(512), dim3(512), 0, stream,
                     Qbuf, Kbuf, Vfrag, mmul, Obuf);
  // output projection + bias, dtype per flag
  hipLaunchKernelGGL((gemm_bt<512, 2>), dim3(4, 64), dim3(256), 0, stream,
                     Obuf, Wpb, bpb, d_out, (bf16_t*)nullptr, flags, 512);
}

// Round 6
// 238.863 us; speedup vs baseline: 1.0294x; 1.0115x over previous
//
#include <hip/hip_runtime.h>
#include <hip/hip_bf16.h>
#include <stdint.h>

// ---- types -----------------------------------------------------------------
typedef __bf16 bf16_t;
typedef __bf16 bf16x8 __attribute__((ext_vector_type(8)));
typedef __bf16 bf16x4 __attribute__((ext_vector_type(4)));
typedef float  f32x4  __attribute__((ext_vector_type(4)));

#define MFMA16(a, b, c) __builtin_amdgcn_mfma_f32_16x16x32_bf16((a), (b), (c), 0, 0, 0)

__device__ __forceinline__ void gload_lds16(const void* g, void* l) {
  __builtin_amdgcn_global_load_lds((const __attribute__((address_space(1))) void*)g,
                                   (__attribute__((address_space(3))) void*)l, 16, 0, 0);
}

// ---- problem constants -----------------------------------------------------
// B=2, N=4096, NY=4096, ENC=768, DEC=512, H=8, D=64, SCALE=0.125
#define QSCALE 0.18033688011112042f
#define NE_X   4194304UL
#define NE_Y   6291456UL
#define NE_WQ  262144UL
#define NE_WKV 786432UL
#define NE_WP  262144UL
#define NE_BP  512UL

// ---- detect dtype + decode mask to multiplicative bf16 (1=keep, 0=masked) --
__global__ void detect_and_mask(const uint16_t* __restrict__ xu,
                                const uint8_t* __restrict__ mk,
                                int* __restrict__ flags, bf16_t* __restrict__ mmul) {
  __shared__ int cbf, c3f1, c3f3, cnz;
  const int t = threadIdx.x;
  if (t == 0) { cbf = 0; c3f1 = 0; c3f3 = 0; cnz = 0; }
  __syncthreads();
  if (blockIdx.x == 0) {
    int local = 0;
    for (int i = t; i < 2048; i += 256) {
      uint16_t u = xu[2 * i];
      int e = (u >> 7) & 0xFF;
      if (u == 0 || (e >= 0x66 && e <= 0x88)) local++;
    }
    atomicAdd(&cbf, local);
  }
  int l1 = 0, l3 = 0, lnz = 0;
  for (int i = t; i < 4096; i += 256) {
    uint8_t b = mk[i];
    int p = i & 3;
    if (p == 1 && b == 0x3F) l1++;
    if (p == 3 && b == 0x3F) l3++;
    if (p != 0 && b != 0) lnz++;
  }
  atomicAdd(&c3f1, l1);
  atomicAdd(&c3f3, l3);
  atomicAdd(&cnz, lnz);
  __syncthreads();
  if (blockIdx.x == 0 && t == 0) flags[0] = (cbf > 1536) ? 1 : 0;
  const int fmt = (c3f1 > 0) ? 2 : (c3f3 > 0) ? 3 : (cnz > 0) ? 0 : 1;  // 0=bool8 1=i32 2=bf16 3=f32
  const int i = blockIdx.x * 256 + t;  // 32 blocks x 256 = 8192
  bool on;
  if (fmt == 0)      on = mk[i] != 0;
  else if (fmt == 1) on = ((const int*)mk)[i] != 0;
  else if (fmt == 2) on = (((const uint16_t*)mk)[i] & 0x7FFF) != 0;
  else               on = ((const float*)mk)[i] != 0.0f;
  mmul[i] = on ? (bf16_t)0.0f : (bf16_t)1.0f;  // mask=true means EXCLUDE
}

// ---- convert all float inputs to packed bf16 workspace (Wq pre-scaled) -----
__global__ void convert_all(const void* __restrict__ x, const void* __restrict__ y,
                            const void* __restrict__ wq, const void* __restrict__ wkv,
                            const void* __restrict__ wp, const void* __restrict__ bp,
                            uint16_t* __restrict__ dst, const int* __restrict__ flags) {
  const size_t E0 = NE_X, E1 = E0 + NE_Y, E2 = E1 + NE_WQ, E3 = E2 + NE_WKV,
               E4 = E3 + NE_WP, E5 = E4 + NE_BP;
  size_t i8 = ((size_t)blockIdx.x * 256 + threadIdx.x) * 8;
  if (i8 >= E5) return;
  const void* src; size_t off;
  if      (i8 < E0) { src = x;   off = i8; }
  else if (i8 < E1) { src = y;   off = i8 - E0; }
  else if (i8 < E2) { src = wq;  off = i8 - E1; }
  else if (i8 < E3) { src = wkv; off = i8 - E2; }
  else if (i8 < E4) { src = wp;  off = i8 - E3; }
  else              { src = bp;  off = i8 - E4; }
  const bool isWq = (i8 >= E1 && i8 < E2);
  if (flags[0] && !isWq) {
    *(uint4*)(dst + i8) = *(const uint4*)((const uint16_t*)src + off);
    return;
  }
  float v[8];
  if (flags[0]) {  // bf16 source (Wq path): unpack
    const uint16_t* u = (const uint16_t*)src + off;
    for (int j = 0; j < 8; ++j) {
      union { uint32_t q; float f; } c; c.q = ((uint32_t)u[j]) << 16; v[j] = c.f;
    }
  } else {
    const float* f = (const float*)src + off;
    float4 a = *(const float4*)f;
    float4 b2 = *(const float4*)(f + 4);
    v[0] = a.x; v[1] = a.y; v[2] = a.z; v[3] = a.w;
    v[4] = b2.x; v[5] = b2.y; v[6] = b2.z; v[7] = b2.w;
  }
  const float sc = isWq ? QSCALE : 1.0f;
  union { bf16_t h[8]; uint4 u; } pk;
  for (int j = 0; j < 8; ++j) pk.h[j] = (bf16_t)(v[j] * sc);
  *(uint4*)(dst + i8) = pk.u;
}

// ---- GEMM: C[M x Nc] = A[M x K] @ W[Nc x K]^T, 128x128 tile, BK=32 ---------
template <int K, int MODE>
__launch_bounds__(256, 2)
__global__ void gemm_bt(const bf16_t* __restrict__ A, const bf16_t* __restrict__ W,
                        const bf16_t* __restrict__ bias, void* __restrict__ C,
                        bf16_t* __restrict__ Vt, const int* __restrict__ flags, int Ncols) {
  __shared__ __align__(16) char lds[16384];
  char* ldsA = lds;
  char* ldsW = lds + 8192;
  const int t = threadIdx.x;
  const int w = t >> 6, lane = t & 63, quad = lane >> 4, l16 = lane & 15;
  const int wr = w >> 1, wc = w & 1;
  const int m0 = blockIdx.y * 128, n0 = blockIdx.x * 128;

  f32x4 acc[4][4] = {};
  const int rowS = t >> 2, uS = t & 3;

  for (int k0 = 0; k0 < K; k0 += 32) {
    __syncthreads();
    for (int i = 0; i < 2; ++i) {
      int row = i * 64 + rowS;
      int c = uS ^ ((row >> 1) & 3);
      gload_lds16(A + (size_t)(m0 + row) * K + k0 + c * 8, ldsA + i * 4096 + w * 1024);
      gload_lds16(W + (size_t)(n0 + row) * K + k0 + c * 8, ldsW + i * 4096 + w * 1024);
    }
    __syncthreads();
    bf16x8 af[4], bfr[4];
    for (int mt = 0; mt < 4; ++mt) {
      int row = wr * 64 + mt * 16 + l16;
      int us = quad ^ ((row >> 1) & 3);
      af[mt] = *(const bf16x8*)(ldsA + row * 64 + us * 16);
    }
    for (int nt = 0; nt < 4; ++nt) {
      int row = wc * 64 + nt * 16 + l16;
      int us = quad ^ ((row >> 1) & 3);
      bfr[nt] = *(const bf16x8*)(ldsW + row * 64 + us * 16);
    }
    for (int mt = 0; mt < 4; ++mt)
      for (int nt = 0; nt < 4; ++nt)
        acc[mt][nt] = MFMA16(af[mt], bfr[nt], acc[mt][nt]);
  }

  const int mbase = m0 + wr * 64;
  for (int nt = 0; nt < 4; ++nt) {
    const int col = n0 + wc * 64 + nt * 16 + l16;
    if (MODE == 1 && col >= 512) {
      const int hd = col - 512;                  // h*64 + d
      const int hh = hd >> 6, d = hd & 63;
      const int dt = d >> 4, l15 = d & 15;
      for (int mt = 0; mt < 4; ++mt) {
        int m = mbase + mt * 16 + quad * 4;      // +r over r
        int bb = m >> 12, keyg = m & 4095;
        int kt = keyg >> 6, keyin = keyg & 63;
        int kc = (keyin >> 5) & 1, jq = (keyin >> 3) & 3, j0 = keyin & 7;  // j0 in {0,4}
        const bf16_t* mmp = bias + bb * 4096 + keyg;
        union { bf16_t h4[4]; uint2 u; } pk;
        for (int r = 0; r < 4; ++r) pk.h4[r] = (bf16_t)(acc[mt][nt][r] * (float)mmp[r]);
        size_t base = (((size_t)(bb * 8 + hh) * 64 + kt) * 8 + dt * 2 + kc) * 1024
                      + (jq * 16 + l15) * 16 + j0 * 2;
        *(uint2*)((char*)Vt + base) = pk.u;
      }
    } else if (MODE == 1) {
      for (int mt = 0; mt < 4; ++mt) {
        int m = mbase + mt * 16 + quad * 4;
        for (int r = 0; r < 4; ++r)
          ((bf16_t*)C)[(size_t)(m + r) * 512 + col] = (bf16_t)acc[mt][nt][r];
      }
    } else if (MODE == 0) {
      for (int mt = 0; mt < 4; ++mt) {
        int m = mbase + mt * 16 + quad * 4;
        for (int r = 0; r < 4; ++r)
          ((bf16_t*)C)[(size_t)(m + r) * Ncols + col] = (bf16_t)acc[mt][nt][r];
      }
    } else {  // MODE 2
      const float bv = (float)bias[col];
      const bool obf = (flags[0] != 0);
      for (int mt = 0; mt < 4; ++mt) {
        int m = mbase + mt * 16 + quad * 4;
        for (int r = 0; r < 4; ++r) {
          float v = acc[mt][nt][r] + bv;
          if (obf) ((bf16_t*)C)[(size_t)(m + r) * Ncols + col] = (bf16_t)v;
          else     ((float*)C)[(size_t)(m + r) * Ncols + col] = v;
        }
      }
    }
  }
}

// ---- fused flash attention, 256 q / block, 32 q / wave, 8 waves ------------
// No online max: scores are bounded (pre-scaled Wq), softmax shift-invariant.
// NG=2 (32q/wave): K fragments amortized over 2 q-groups. V from GLOBAL in
// fragment order (L1-hot, parallel TA pipe) — LDS pipe carries only K + P.
// T4: raw s_barrier + counted vmcnt(6) (never 0 until tail), 10-slot K ring,
// staging issued AFTER the pair's V loads so vf-use waits stay counted.
// h=bid&7 pins each head to one XCD; grid 256 = 1 block/CU.
__launch_bounds__(512, 2)
__global__ void attn(const bf16_t* __restrict__ Qb, const bf16_t* __restrict__ Kb,
                     const bf16_t* __restrict__ Vfb, const bf16_t* __restrict__ mmul,
                     bf16_t* __restrict__ Ob) {
  const int t = threadIdx.x, w = t >> 6, lane = t & 63, quad = lane >> 4, l16 = lane & 15;
  const int bid = blockIdx.x;
  const int h = bid & 7;            // XCD-pinned
  const int b = (bid >> 3) & 1;
  const int q0 = (bid >> 4) * 256;  // 16 q-blocks of 256

  __shared__ __align__(16) char lds[114688];
  // K ring: 10 slots x 8KB = [0, 81920); tile kt -> slot kt%10.
  // P: [81920, 114688) = 8 waves x 4KB (2KB per ng).
  // Q staging overlays ring slots 6..9 ([49152, 81920), 32KB).
  char* Pw = lds + 81920 + w * 4096;
  char* Qs = lds + 49152;

  const bf16_t* Kbase = Kb + (size_t)(b * 4096) * 512 + h * 64;
  const char* Vfbase = (const char*)Vfb + (size_t)(b * 8 + h) * 524288;  // 64*8*1024

  const int srow = t >> 3;            // 0..63 staging row
  const int sc8 = t & 7;

  auto stage_tile = [&](int kt, int slot) {
    int c = sc8 ^ (srow & 7);
    gload_lds16(Kbase + (size_t)(kt * 64 + srow) * 512 + c * 8,
                lds + slot * 8192 + w * 1024);
  };

  // ---- prologue: stage K tiles 0..5 (slots 0..5) + Q (overlay slots 6..9) --
  for (int kt = 0; kt < 6; ++kt) stage_tile(kt, kt);
  for (int i = 0; i < 4; ++i) {
    int row = i * 64 + srow;
    int c = sc8 ^ (row & 7);
    gload_lds16(Qb + (size_t)(b * 4096 + q0 + row) * 512 + h * 64 + c * 8,
                Qs + i * 8192 + w * 1024);
  }
  asm volatile("s_waitcnt vmcnt(0)" ::: "memory");
  __builtin_amdgcn_sched_barrier(0);
  __builtin_amdgcn_s_barrier();

  bf16x8 qf[2][2];
  for (int ng = 0; ng < 2; ++ng)
    for (int kc = 0; kc < 2; ++kc) {
      int row = 32 * w + 16 * ng + l16;
      int u = (4 * kc + quad) ^ (l16 & 7);
      qf[ng][kc] = *(const bf16x8*)(Qs + row * 128 + u * 16);
    }
  asm volatile("s_waitcnt lgkmcnt(0)" ::: "memory");
  __builtin_amdgcn_sched_barrier(0);
  __builtin_amdgcn_s_barrier();
  // stage tiles 6,7 into slots 6,7 (Q region now dead)
  stage_tile(6, 6);
  stage_tile(7, 7);

  f32x4 o[2][4] = {};
  f32x4 lacc[2] = {};
  const int u0 = quad ^ (l16 & 7), u1 = (4 + quad) ^ (l16 & 7);

  auto process = [&](int kt, int slot) {
    const int kt0 = kt * 64;
    // mask + V fragments from global (L1-hot), issued first
    bf16x8 mf0 = *(const bf16x8*)(mmul + b * 4096 + kt0 + quad * 8);
    bf16x8 mf1 = *(const bf16x8*)(mmul + b * 4096 + kt0 + 32 + quad * 8);
    const char* Vtile = Vfbase + (size_t)kt * 8192;
    bf16x8 vf[4][2];
    for (int dt = 0; dt < 4; ++dt)
      for (int kc = 0; kc < 2; ++kc)
        vf[dt][kc] = *(const bf16x8*)(Vtile + (dt * 2 + kc) * 1024 + lane * 16);
    // K fragments (LDS)
    const char* Kl = lds + slot * 8192;
    bf16x8 kf[4][2];
    for (int mt = 0; mt < 4; ++mt) {
      kf[mt][0] = *(const bf16x8*)(Kl + (mt * 16 + l16) * 128 + u0 * 16);
      kf[mt][1] = *(const bf16x8*)(Kl + (mt * 16 + l16) * 128 + u1 * 16);
    }
    // QK for both q-groups (MFMA cluster)
    f32x4 z[2][4];
    __builtin_amdgcn_s_setprio(1);
    for (int ng = 0; ng < 2; ++ng)
      for (int mt = 0; mt < 4; ++mt) {
        f32x4 zz = {};
        zz = MFMA16(kf[mt][0], qf[ng][0], zz);
        z[ng][mt] = MFMA16(kf[mt][1], qf[ng][1], zz);
      }
    __builtin_amdgcn_s_setprio(0);
    // softmax -> P (per-wave LDS, 2KB per ng) -> pf -> l + PV
    for (int ng = 0; ng < 2; ++ng) {
      char* Pn = Pw + ng * 2048;
      for (int mt = 0; mt < 4; ++mt) {
        bf16x4 pk;
        pk.x = (bf16_t)__builtin_amdgcn_exp2f(z[ng][mt][0]);
        pk.y = (bf16_t)__builtin_amdgcn_exp2f(z[ng][mt][1]);
        pk.z = (bf16_t)__builtin_amdgcn_exp2f(z[ng][mt][2]);
        pk.w = (bf16_t)__builtin_amdgcn_exp2f(z[ng][mt][3]);
        int c2 = (2 * mt + (quad >> 1)) ^ (l16 & 7);
        *(bf16x4*)(Pn + l16 * 128 + c2 * 16 + (quad & 1) * 8) = pk;
      }
      bf16x8 pf0 = *(const bf16x8*)(Pn + l16 * 128 + u0 * 16);
      bf16x8 pf1 = *(const bf16x8*)(Pn + l16 * 128 + u1 * 16);
      __builtin_amdgcn_s_setprio(1);
      lacc[ng] = MFMA16(pf0, mf0, lacc[ng]);
      lacc[ng] = MFMA16(pf1, mf1, lacc[ng]);
      for (int dt = 0; dt < 4; ++dt) {
        o[ng][dt] = MFMA16(pf0, vf[dt][0], o[ng][dt]);
        o[ng][dt] = MFMA16(pf1, vf[dt][1], o[ng][dt]);
      }
      __builtin_amdgcn_s_setprio(0);
    }
  };

  // ---- main loop: 32 pairs, 2 raw barriers/pair, counted vmcnt -------------
  int sA = 0, sB = 1;  // slots of tiles 2pg, 2pg+1 (kt % 10)
  for (int pg = 0; pg < 32; ++pg) {
    // staged-K completion guard: outstanding staging <= 6 => tiles <= 2pg+1 done
    if (pg < 29) { asm volatile("s_waitcnt vmcnt(6)" ::: "memory"); }
    else         { asm volatile("s_waitcnt vmcnt(0)" ::: "memory"); }
    __builtin_amdgcn_sched_barrier(0);
    __builtin_amdgcn_s_barrier();
    const int ktA = pg * 2;
    process(ktA, sA);
    process(ktA + 1, sB);
    // stage tiles ktA+8, ktA+9 (slots (sA+8)%10, (sB+8)%10): ring distance
    // guarantees no conflict with slots being read this pair. Issued BEFORE
    // the end barrier so vf-use waits above stay counted (not vmcnt(0)).
    if (ktA + 8 < 64) {
      int s8A = sA + 8; if (s8A >= 10) s8A -= 10;
      int s8B = sB + 8; if (s8B >= 10) s8B -= 10;
      stage_tile(ktA + 8, s8A);
      stage_tile(ktA + 9, s8B);
    }
    __builtin_amdgcn_s_barrier();  // readers done before those slots rewritten
    sA += 2; if (sA >= 10) sA -= 10;
    sB += 2; if (sB >= 10) sB -= 10;
  }

  // epilogue: O / l, store bf16 (C-layout, no shuffles)
  for (int ng = 0; ng < 2; ++ng) {
    float inv[4];
    for (int r = 0; r < 4; ++r) inv[r] = 1.0f / lacc[ng][r];
    for (int dt = 0; dt < 4; ++dt)
      for (int r = 0; r < 4; ++r) {
        int q = q0 + 32 * w + 16 * ng + quad * 4 + r;
        int col = h * 64 + dt * 16 + l16;
        Ob[(size_t)(b * 4096 + q) * 512 + col] = (bf16_t)(o[ng][dt][r] * inv[r]);
      }
  }
}

// ---- launch ----------------------------------------------------------------
extern "C" void kernel_launch(void* const* d_in, const int* in_sizes, int n_in,
                              void* d_out, int out_size, void* d_ws, size_t ws_size,
                              hipStream_t stream) {
  const void* x   = d_in[0];
  const void* y   = d_in[1];
  const void* msk = d_in[2];
  const void* Wq  = d_in[3];
  const void* Wkv = d_in[4];
  const void* Wp  = d_in[5];
  const void* bp  = d_in[6];

  char* ws = (char*)d_ws;
  bf16_t* Xb   = (bf16_t*)(ws + 0);           //  8 MB  [8192 x 512]
  bf16_t* Yb   = (bf16_t*)(ws + 8388608);     // 12 MB  [8192 x 768]
  bf16_t* Wqb  = (bf16_t*)(ws + 20971520);    // 0.5 MB (pre-scaled by QSCALE)
  bf16_t* Wkvb = (bf16_t*)(ws + 21495808);    // 1.5 MB
  bf16_t* Wpb  = (bf16_t*)(ws + 23068672);    // 0.5 MB
  bf16_t* bpb  = (bf16_t*)(ws + 23592960);    // 1 KB
  bf16_t* mmul = (bf16_t*)(ws + 23593984);    // 16 KB  [2][4096] 0/1
  int*    flags = (int*)(ws + 23610368);      // 64 B
  bf16_t* Kbuf  = (bf16_t*)(ws + 25165824);   //  8 MB  [8192 x 512]
  bf16_t* Vfrag = (bf16_t*)(ws + 33554432);   //  8 MB  fragment-order V, mask-zeroed
  bf16_t* Qbuf  = (bf16_t*)(ws + 8388608);    //  8 MB  (aliases Yb, dead by then)
  bf16_t* Obuf  = (bf16_t*)(ws + 0);          //  8 MB  (aliases Xb, dead by then)

  hipLaunchKernelGGL(detect_and_mask, dim3(32), dim3(256), 0, stream,
                     (const uint16_t*)x, (const uint8_t*)msk, flags, mmul);
  hipLaunchKernelGGL(convert_all, dim3(5761), dim3(256), 0, stream,
                     x, y, Wq, Wkv, Wp, bp, (uint16_t*)ws, flags);
  // KV projection; V side written in MFMA fragment order + mask-zeroed
  hipLaunchKernelGGL((gemm_bt<768, 1>), dim3(8, 64), dim3(256), 0, stream,
                     Yb, Wkvb, mmul, (void*)Kbuf, Vfrag, flags, 1024);
  // Q projection (scores pre-scaled via Wqb)
  hipLaunchKernelGGL((gemm_bt<512, 0>), dim3(4, 64), dim3(256), 0, stream,
                     Xb, Wqb, (const bf16_t*)nullptr, (void*)Qbuf, (bf16_t*)nullptr, flags, 512);
  // fused attention (512 threads = 8 waves x 32q, grid 256, XCD-pinned heads)
  hipLaunchKernelGGL(attn, dim3(256), dim3(512), 0, stream,
                     Qbuf, Kbuf, Vfrag, mmul, Obuf);
  // output projection + bias, dtype per flag
  hipLaunchKernelGGL((gemm_bt<512, 2>), dim3(4, 64), dim3(256), 0, stream,
                     Obuf, Wpb, bpb, d_out, (bf16_t*)nullptr, flags, 512);
}

// Round 7
// 231.858 us; speedup vs baseline: 1.0605x; 1.0302x over previous
//
#include <hip/hip_runtime.h>
#include <hip/hip_bf16.h>
#include <stdint.h>

// ---- types -----------------------------------------------------------------
typedef __bf16 bf16_t;
typedef __bf16 bf16x8 __attribute__((ext_vector_type(8)));
typedef __bf16 bf16x4 __attribute__((ext_vector_type(4)));
typedef float  f32x4  __attribute__((ext_vector_type(4)));

#define MFMA16(a, b, c) __builtin_amdgcn_mfma_f32_16x16x32_bf16((a), (b), (c), 0, 0, 0)

__device__ __forceinline__ void gload_lds16(const void* g, void* l) {
  __builtin_amdgcn_global_load_lds((const __attribute__((address_space(1))) void*)g,
                                   (__attribute__((address_space(3))) void*)l, 16, 0, 0);
}

// ---- problem constants -----------------------------------------------------
// B=2, N=4096, NY=4096, ENC=768, DEC=512, H=8, D=64, SCALE=0.125
#define QSCALE 0.18033688011112042f
#define NE_X   4194304UL
#define NE_Y   6291456UL
#define NE_WQ  262144UL
#define NE_WKV 786432UL
#define NE_WP  262144UL
#define NE_BP  512UL

// ---- detect dtype + decode mask to multiplicative bf16 (1=keep, 0=masked) --
__global__ void detect_and_mask(const uint16_t* __restrict__ xu,
                                const uint8_t* __restrict__ mk,
                                int* __restrict__ flags, bf16_t* __restrict__ mmul) {
  __shared__ int cbf, c3f1, c3f3, cnz;
  const int t = threadIdx.x;
  if (t == 0) { cbf = 0; c3f1 = 0; c3f3 = 0; cnz = 0; }
  __syncthreads();
  if (blockIdx.x == 0) {
    int local = 0;
    for (int i = t; i < 2048; i += 256) {
      uint16_t u = xu[2 * i];
      int e = (u >> 7) & 0xFF;
      if (u == 0 || (e >= 0x66 && e <= 0x88)) local++;
    }
    atomicAdd(&cbf, local);
  }
  int l1 = 0, l3 = 0, lnz = 0;
  for (int i = t; i < 4096; i += 256) {
    uint8_t b = mk[i];
    int p = i & 3;
    if (p == 1 && b == 0x3F) l1++;
    if (p == 3 && b == 0x3F) l3++;
    if (p != 0 && b != 0) lnz++;
  }
  atomicAdd(&c3f1, l1);
  atomicAdd(&c3f3, l3);
  atomicAdd(&cnz, lnz);
  __syncthreads();
  if (blockIdx.x == 0 && t == 0) flags[0] = (cbf > 1536) ? 1 : 0;
  const int fmt = (c3f1 > 0) ? 2 : (c3f3 > 0) ? 3 : (cnz > 0) ? 0 : 1;  // 0=bool8 1=i32 2=bf16 3=f32
  const int i = blockIdx.x * 256 + t;  // 32 blocks x 256 = 8192
  bool on;
  if (fmt == 0)      on = mk[i] != 0;
  else if (fmt == 1) on = ((const int*)mk)[i] != 0;
  else if (fmt == 2) on = (((const uint16_t*)mk)[i] & 0x7FFF) != 0;
  else               on = ((const float*)mk)[i] != 0.0f;
  mmul[i] = on ? (bf16_t)0.0f : (bf16_t)1.0f;  // mask=true means EXCLUDE
}

// ---- convert all float inputs to packed bf16 workspace (Wq pre-scaled) -----
__global__ void convert_all(const void* __restrict__ x, const void* __restrict__ y,
                            const void* __restrict__ wq, const void* __restrict__ wkv,
                            const void* __restrict__ wp, const void* __restrict__ bp,
                            uint16_t* __restrict__ dst, const int* __restrict__ flags) {
  const size_t E0 = NE_X, E1 = E0 + NE_Y, E2 = E1 + NE_WQ, E3 = E2 + NE_WKV,
               E4 = E3 + NE_WP, E5 = E4 + NE_BP;
  size_t i8 = ((size_t)blockIdx.x * 256 + threadIdx.x) * 8;
  if (i8 >= E5) return;
  const void* src; size_t off;
  if      (i8 < E0) { src = x;   off = i8; }
  else if (i8 < E1) { src = y;   off = i8 - E0; }
  else if (i8 < E2) { src = wq;  off = i8 - E1; }
  else if (i8 < E3) { src = wkv; off = i8 - E2; }
  else if (i8 < E4) { src = wp;  off = i8 - E3; }
  else              { src = bp;  off = i8 - E4; }
  const bool isWq = (i8 >= E1 && i8 < E2);
  if (flags[0] && !isWq) {
    *(uint4*)(dst + i8) = *(const uint4*)((const uint16_t*)src + off);
    return;
  }
  float v[8];
  if (flags[0]) {  // bf16 source (Wq path): unpack
    const uint16_t* u = (const uint16_t*)src + off;
    for (int j = 0; j < 8; ++j) {
      union { uint32_t q; float f; } c; c.q = ((uint32_t)u[j]) << 16; v[j] = c.f;
    }
  } else {
    const float* f = (const float*)src + off;
    float4 a = *(const float4*)f;
    float4 b2 = *(const float4*)(f + 4);
    v[0] = a.x; v[1] = a.y; v[2] = a.z; v[3] = a.w;
    v[4] = b2.x; v[5] = b2.y; v[6] = b2.z; v[7] = b2.w;
  }
  const float sc = isWq ? QSCALE : 1.0f;
  union { bf16_t h[8]; uint4 u; } pk;
  for (int j = 0; j < 8; ++j) pk.h[j] = (bf16_t)(v[j] * sc);
  *(uint4*)(dst + i8) = pk.u;
}

// ---- GEMM: C[M x Nc] = A[M x K] @ W[Nc x K]^T, 128x128 tile, BK=32 ---------
// 2-phase double-buffered K-loop: stage tile ks+1 into buf^1, counted
// vmcnt(4) (the 4 older gload_lds of buf), raw barriers. Staging latency
// hides under the previous tile's MFMA instead of being drained every step.
template <int K, int MODE>
__launch_bounds__(256, 2)
__global__ void gemm_bt(const bf16_t* __restrict__ A, const bf16_t* __restrict__ W,
                        const bf16_t* __restrict__ bias, void* __restrict__ C,
                        bf16_t* __restrict__ Vt, const int* __restrict__ flags, int Ncols) {
  __shared__ __align__(16) char lds[32768];   // 2 bufs x (A 8KB + W 8KB)
  const int t = threadIdx.x;
  const int w = t >> 6, lane = t & 63, quad = lane >> 4, l16 = lane & 15;
  const int wr = w >> 1, wc = w & 1;
  const int m0 = blockIdx.y * 128, n0 = blockIdx.x * 128;

  f32x4 acc[4][4] = {};
  const int rowS = t >> 2, uS = t & 3;
  constexpr int NK = K / 32;

  auto stage = [&](int ks, int buf) {
    char* ldsA = lds + buf * 16384;
    char* ldsW = ldsA + 8192;
    const int k0 = ks * 32;
    for (int i = 0; i < 2; ++i) {
      int row = i * 64 + rowS;
      int c = uS ^ ((row >> 1) & 3);
      gload_lds16(A + (size_t)(m0 + row) * K + k0 + c * 8, ldsA + i * 4096 + w * 1024);
      gload_lds16(W + (size_t)(n0 + row) * K + k0 + c * 8, ldsW + i * 4096 + w * 1024);
    }
  };

  stage(0, 0);
  for (int ks = 0; ks < NK; ++ks) {
    const int cur = ks & 1;
    if (ks + 1 < NK) {
      stage(ks + 1, cur ^ 1);                       // issue next-tile loads
      asm volatile("s_waitcnt vmcnt(4)" ::: "memory");  // drain cur's 4 loads only
    } else {
      asm volatile("s_waitcnt vmcnt(0)" ::: "memory");
    }
    __builtin_amdgcn_sched_barrier(0);
    __builtin_amdgcn_s_barrier();                   // cur buffer visible to all
    const char* ldsA = lds + cur * 16384;
    const char* ldsW = ldsA + 8192;
    bf16x8 af[4], bfr[4];
    for (int mt = 0; mt < 4; ++mt) {
      int row = wr * 64 + mt * 16 + l16;
      int us = quad ^ ((row >> 1) & 3);
      af[mt] = *(const bf16x8*)(ldsA + row * 64 + us * 16);
    }
    for (int nt = 0; nt < 4; ++nt) {
      int row = wc * 64 + nt * 16 + l16;
      int us = quad ^ ((row >> 1) & 3);
      bfr[nt] = *(const bf16x8*)(ldsW + row * 64 + us * 16);
    }
    for (int mt = 0; mt < 4; ++mt)
      for (int nt = 0; nt < 4; ++nt)
        acc[mt][nt] = MFMA16(af[mt], bfr[nt], acc[mt][nt]);
    __builtin_amdgcn_s_barrier();                   // reads done before buf reuse
  }

  const int mbase = m0 + wr * 64;
  for (int nt = 0; nt < 4; ++nt) {
    const int col = n0 + wc * 64 + nt * 16 + l16;
    if (MODE == 1 && col >= 512) {
      const int hd = col - 512;                  // h*64 + d
      const int hh = hd >> 6, d = hd & 63;
      const int dt = d >> 4, l15 = d & 15;
      for (int mt = 0; mt < 4; ++mt) {
        int m = mbase + mt * 16 + quad * 4;      // +r over r
        int bb = m >> 12, keyg = m & 4095;
        int kt = keyg >> 6, keyin = keyg & 63;
        int kc = (keyin >> 5) & 1, jq = (keyin >> 3) & 3, j0 = keyin & 7;  // j0 in {0,4}
        const bf16_t* mmp = bias + bb * 4096 + keyg;
        union { bf16_t h4[4]; uint2 u; } pk;
        for (int r = 0; r < 4; ++r) pk.h4[r] = (bf16_t)(acc[mt][nt][r] * (float)mmp[r]);
        size_t base = (((size_t)(bb * 8 + hh) * 64 + kt) * 8 + dt * 2 + kc) * 1024
                      + (jq * 16 + l15) * 16 + j0 * 2;
        *(uint2*)((char*)Vt + base) = pk.u;
      }
    } else if (MODE == 1) {
      for (int mt = 0; mt < 4; ++mt) {
        int m = mbase + mt * 16 + quad * 4;
        for (int r = 0; r < 4; ++r)
          ((bf16_t*)C)[(size_t)(m + r) * 512 + col] = (bf16_t)acc[mt][nt][r];
      }
    } else if (MODE == 0) {
      for (int mt = 0; mt < 4; ++mt) {
        int m = mbase + mt * 16 + quad * 4;
        for (int r = 0; r < 4; ++r)
          ((bf16_t*)C)[(size_t)(m + r) * Ncols + col] = (bf16_t)acc[mt][nt][r];
      }
    } else {  // MODE 2
      const float bv = (float)bias[col];
      const bool obf = (flags[0] != 0);
      for (int mt = 0; mt < 4; ++mt) {
        int m = mbase + mt * 16 + quad * 4;
        for (int r = 0; r < 4; ++r) {
          float v = acc[mt][nt][r] + bv;
          if (obf) ((bf16_t*)C)[(size_t)(m + r) * Ncols + col] = (bf16_t)v;
          else     ((float*)C)[(size_t)(m + r) * Ncols + col] = v;
        }
      }
    }
  }
}

// ---- fused flash attention, 256 q / block, 32 q / wave, 8 waves ------------
// (unchanged from R6 best: 88.8 us)
__launch_bounds__(512, 2)
__global__ void attn(const bf16_t* __restrict__ Qb, const bf16_t* __restrict__ Kb,
                     const bf16_t* __restrict__ Vfb, const bf16_t* __restrict__ mmul,
                     bf16_t* __restrict__ Ob) {
  const int t = threadIdx.x, w = t >> 6, lane = t & 63, quad = lane >> 4, l16 = lane & 15;
  const int bid = blockIdx.x;
  const int h = bid & 7;            // XCD-pinned
  const int b = (bid >> 3) & 1;
  const int q0 = (bid >> 4) * 256;  // 16 q-blocks of 256

  __shared__ __align__(16) char lds[114688];
  // K ring: 10 slots x 8KB = [0, 81920); tile kt -> slot kt%10.
  // P: [81920, 114688) = 8 waves x 4KB (2KB per ng).
  // Q staging overlays ring slots 6..9 ([49152, 81920), 32KB).
  char* Pw = lds + 81920 + w * 4096;
  char* Qs = lds + 49152;

  const bf16_t* Kbase = Kb + (size_t)(b * 4096) * 512 + h * 64;
  const char* Vfbase = (const char*)Vfb + (size_t)(b * 8 + h) * 524288;  // 64*8*1024

  const int srow = t >> 3;            // 0..63 staging row
  const int sc8 = t & 7;

  auto stage_tile = [&](int kt, int slot) {
    int c = sc8 ^ (srow & 7);
    gload_lds16(Kbase + (size_t)(kt * 64 + srow) * 512 + c * 8,
                lds + slot * 8192 + w * 1024);
  };

  // ---- prologue: stage K tiles 0..5 (slots 0..5) + Q (overlay slots 6..9) --
  for (int kt = 0; kt < 6; ++kt) stage_tile(kt, kt);
  for (int i = 0; i < 4; ++i) {
    int row = i * 64 + srow;
    int c = sc8 ^ (row & 7);
    gload_lds16(Qb + (size_t)(b * 4096 + q0 + row) * 512 + h * 64 + c * 8,
                Qs + i * 8192 + w * 1024);
  }
  asm volatile("s_waitcnt vmcnt(0)" ::: "memory");
  __builtin_amdgcn_sched_barrier(0);
  __builtin_amdgcn_s_barrier();

  bf16x8 qf[2][2];
  for (int ng = 0; ng < 2; ++ng)
    for (int kc = 0; kc < 2; ++kc) {
      int row = 32 * w + 16 * ng + l16;
      int u = (4 * kc + quad) ^ (l16 & 7);
      qf[ng][kc] = *(const bf16x8*)(Qs + row * 128 + u * 16);
    }
  asm volatile("s_waitcnt lgkmcnt(0)" ::: "memory");
  __builtin_amdgcn_sched_barrier(0);
  __builtin_amdgcn_s_barrier();
  // stage tiles 6,7 into slots 6,7 (Q region now dead)
  stage_tile(6, 6);
  stage_tile(7, 7);

  f32x4 o[2][4] = {};
  f32x4 lacc[2] = {};
  const int u0 = quad ^ (l16 & 7), u1 = (4 + quad) ^ (l16 & 7);

  auto process = [&](int kt, int slot) {
    const int kt0 = kt * 64;
    // mask + V fragments from global (L1-hot), issued first
    bf16x8 mf0 = *(const bf16x8*)(mmul + b * 4096 + kt0 + quad * 8);
    bf16x8 mf1 = *(const bf16x8*)(mmul + b * 4096 + kt0 + 32 + quad * 8);
    const char* Vtile = Vfbase + (size_t)kt * 8192;
    bf16x8 vf[4][2];
    for (int dt = 0; dt < 4; ++dt)
      for (int kc = 0; kc < 2; ++kc)
        vf[dt][kc] = *(const bf16x8*)(Vtile + (dt * 2 + kc) * 1024 + lane * 16);
    // K fragments (LDS)
    const char* Kl = lds + slot * 8192;
    bf16x8 kf[4][2];
    for (int mt = 0; mt < 4; ++mt) {
      kf[mt][0] = *(const bf16x8*)(Kl + (mt * 16 + l16) * 128 + u0 * 16);
      kf[mt][1] = *(const bf16x8*)(Kl + (mt * 16 + l16) * 128 + u1 * 16);
    }
    // QK for both q-groups (MFMA cluster)
    f32x4 z[2][4];
    __builtin_amdgcn_s_setprio(1);
    for (int ng = 0; ng < 2; ++ng)
      for (int mt = 0; mt < 4; ++mt) {
        f32x4 zz = {};
        zz = MFMA16(kf[mt][0], qf[ng][0], zz);
        z[ng][mt] = MFMA16(kf[mt][1], qf[ng][1], zz);
      }
    __builtin_amdgcn_s_setprio(0);
    // softmax -> P (per-wave LDS, 2KB per ng) -> pf -> l + PV
    for (int ng = 0; ng < 2; ++ng) {
      char* Pn = Pw + ng * 2048;
      for (int mt = 0; mt < 4; ++mt) {
        bf16x4 pk;
        pk.x = (bf16_t)__builtin_amdgcn_exp2f(z[ng][mt][0]);
        pk.y = (bf16_t)__builtin_amdgcn_exp2f(z[ng][mt][1]);
        pk.z = (bf16_t)__builtin_amdgcn_exp2f(z[ng][mt][2]);
        pk.w = (bf16_t)__builtin_amdgcn_exp2f(z[ng][mt][3]);
        int c2 = (2 * mt + (quad >> 1)) ^ (l16 & 7);
        *(bf16x4*)(Pn + l16 * 128 + c2 * 16 + (quad & 1) * 8) = pk;
      }
      bf16x8 pf0 = *(const bf16x8*)(Pn + l16 * 128 + u0 * 16);
      bf16x8 pf1 = *(const bf16x8*)(Pn + l16 * 128 + u1 * 16);
      __builtin_amdgcn_s_setprio(1);
      lacc[ng] = MFMA16(pf0, mf0, lacc[ng]);
      lacc[ng] = MFMA16(pf1, mf1, lacc[ng]);
      for (int dt = 0; dt < 4; ++dt) {
        o[ng][dt] = MFMA16(pf0, vf[dt][0], o[ng][dt]);
        o[ng][dt] = MFMA16(pf1, vf[dt][1], o[ng][dt]);
      }
      __builtin_amdgcn_s_setprio(0);
    }
  };

  // ---- main loop: 32 pairs, 2 raw barriers/pair, counted vmcnt -------------
  int sA = 0, sB = 1;  // slots of tiles 2pg, 2pg+1 (kt % 10)
  for (int pg = 0; pg < 32; ++pg) {
    // staged-K completion guard: outstanding staging <= 6 => tiles <= 2pg+1 done
    if (pg < 29) { asm volatile("s_waitcnt vmcnt(6)" ::: "memory"); }
    else         { asm volatile("s_waitcnt vmcnt(0)" ::: "memory"); }
    __builtin_amdgcn_sched_barrier(0);
    __builtin_amdgcn_s_barrier();
    const int ktA = pg * 2;
    process(ktA, sA);
    process(ktA + 1, sB);
    // stage tiles ktA+8, ktA+9 (slots (sA+8)%10, (sB+8)%10): ring distance
    // guarantees no conflict with slots being read this pair. Issued BEFORE
    // the end barrier so vf-use waits above stay counted (not vmcnt(0)).
    if (ktA + 8 < 64) {
      int s8A = sA + 8; if (s8A >= 10) s8A -= 10;
      int s8B = sB + 8; if (s8B >= 10) s8B -= 10;
      stage_tile(ktA + 8, s8A);
      stage_tile(ktA + 9, s8B);
    }
    __builtin_amdgcn_s_barrier();  // readers done before those slots rewritten
    sA += 2; if (sA >= 10) sA -= 10;
    sB += 2; if (sB >= 10) sB -= 10;
  }

  // epilogue: O / l, store bf16 (C-layout, no shuffles)
  for (int ng = 0; ng < 2; ++ng) {
    float inv[4];
    for (int r = 0; r < 4; ++r) inv[r] = 1.0f / lacc[ng][r];
    for (int dt = 0; dt < 4; ++dt)
      for (int r = 0; r < 4; ++r) {
        int q = q0 + 32 * w + 16 * ng + quad * 4 + r;
        int col = h * 64 + dt * 16 + l16;
        Ob[(size_t)(b * 4096 + q) * 512 + col] = (bf16_t)(o[ng][dt][r] * inv[r]);
      }
  }
}

// ---- launch ----------------------------------------------------------------
extern "C" void kernel_launch(void* const* d_in, const int* in_sizes, int n_in,
                              void* d_out, int out_size, void* d_ws, size_t ws_size,
                              hipStream_t stream) {
  const void* x   = d_in[0];
  const void* y   = d_in[1];
  const void* msk = d_in[2];
  const void* Wq  = d_in[3];
  const void* Wkv = d_in[4];
  const void* Wp  = d_in[5];
  const void* bp  = d_in[6];

  char* ws = (char*)d_ws;
  bf16_t* Xb   = (bf16_t*)(ws + 0);           //  8 MB  [8192 x 512]
  bf16_t* Yb   = (bf16_t*)(ws + 8388608);     // 12 MB  [8192 x 768]
  bf16_t* Wqb  = (bf16_t*)(ws + 20971520);    // 0.5 MB (pre-scaled by QSCALE)
  bf16_t* Wkvb = (bf16_t*)(ws + 21495808);    // 1.5 MB
  bf16_t* Wpb  = (bf16_t*)(ws + 23068672);    // 0.5 MB
  bf16_t* bpb  = (bf16_t*)(ws + 23592960);    // 1 KB
  bf16_t* mmul = (bf16_t*)(ws + 23593984);    // 16 KB  [2][4096] 0/1
  int*    flags = (int*)(ws + 23610368);      // 64 B
  bf16_t* Kbuf  = (bf16_t*)(ws + 25165824);   //  8 MB  [8192 x 512]
  bf16_t* Vfrag = (bf16_t*)(ws + 33554432);   //  8 MB  fragment-order V, mask-zeroed
  bf16_t* Qbuf  = (bf16_t*)(ws + 8388608);    //  8 MB  (aliases Yb, dead by then)
  bf16_t* Obuf  = (bf16_t*)(ws + 0);          //  8 MB  (aliases Xb, dead by then)

  hipLaunchKernelGGL(detect_and_mask, dim3(32), dim3(256), 0, stream,
                     (const uint16_t*)x, (const uint8_t*)msk, flags, mmul);
  hipLaunchKernelGGL(convert_all, dim3(5761), dim3(256), 0, stream,
                     x, y, Wq, Wkv, Wp, bp, (uint16_t*)ws, flags);
  // KV projection; V side written in MFMA fragment order + mask-zeroed
  hipLaunchKernelGGL((gemm_bt<768, 1>), dim3(8, 64), dim3(256), 0, stream,
                     Yb, Wkvb, mmul, (void*)Kbuf, Vfrag, flags, 1024);
  // Q projection (scores pre-scaled via Wqb)
  hipLaunchKernelGGL((gemm_bt<512, 0>), dim3(4, 64), dim3(256), 0, stream,
                     Xb, Wqb, (const bf16_t*)nullptr, (void*)Qbuf, (bf16_t*)nullptr, flags, 512);
  // fused attention (512 threads = 8 waves x 32q, grid 256, XCD-pinned heads)
  hipLaunchKernelGGL(attn, dim3(256), dim3(512), 0, stream,
                     Qbuf, Kbuf, Vfrag, mmul, Obuf);
  // output projection + bias, dtype per flag
  hipLaunchKernelGGL((gemm_bt<512, 2>), dim3(4, 64), dim3(256), 0, stream,
                     Obuf, Wpb, bpb, d_out, (bf16_t*)nullptr, flags, 512);
}